// Round 5
// baseline (274.180 us; speedup 1.0000x reference)
//
#include <hip/hip_runtime.h>
#include <math.h>

#define N 4096
#define THREADS 256
#define BATCH 8192

// XOR swizzle: bijection on [0,4096) making all three LDS access families
// (stride-256 reads, 16-contiguous writes, stride-16 writes) bank-minimal.
// MEASURED conflict-free (rounds 0/3/4: SQ_LDS_BANK_CONFLICT == 0) -- do not touch.
#define SWZ(i) ((i) ^ (((i) >> 4) & 15))
// dft16 stores X_p at slot IDX16(p) (base-4 digit swap; involution)
#define IDX16(p) ((((p) & 3) << 2) | ((p) >> 2))

__device__ __forceinline__ float2 cmul(float2 a, float2 b) {
    return make_float2(fmaf(a.x, b.x, -(a.y * b.y)), fmaf(a.x, b.y, a.y * b.x));
}

// radix-4 butterfly at v[base + r*stride]; forward uses w4 = -i, inverse +i
template<bool INV>
__device__ __forceinline__ void dft4(float2* v, int base, int stride) {
    float2 a = v[base], b = v[base + stride], c = v[base + 2 * stride], d = v[base + 3 * stride];
    float2 t0 = make_float2(a.x + c.x, a.y + c.y);
    float2 t1 = make_float2(a.x - c.x, a.y - c.y);
    float2 t2 = make_float2(b.x + d.x, b.y + d.y);
    float2 t3 = make_float2(b.x - d.x, b.y - d.y);
    float2 j3 = INV ? make_float2(-t3.y, t3.x) : make_float2(t3.y, -t3.x);
    v[base]              = make_float2(t0.x + t2.x, t0.y + t2.y);
    v[base + stride]     = make_float2(t1.x + j3.x, t1.y + j3.y);
    v[base + 2 * stride] = make_float2(t0.x - t2.x, t0.y - t2.y);
    v[base + 3 * stride] = make_float2(t1.x - j3.x, t1.y - j3.y);
}

// internal W16^{n1*k2} twiddles; slot set is symmetric under n1<->k2 so this
// works for both dft16 and dft16_perm.
template<bool INV>
__device__ __forceinline__ void tw16(float2* v) {
    const float C1 = 0.9238795325112867f;
    const float S1 = 0.3826834323650898f;
    const float R2 = 0.7071067811865476f;
    const float s = INV ? 1.0f : -1.0f;
    const float2 W1 = make_float2(C1, s * S1);
    const float2 W2 = make_float2(R2, s * R2);
    const float2 W3 = make_float2(S1, s * C1);
    const float2 W6 = make_float2(-R2, s * R2);
    const float2 W9 = make_float2(-C1, -s * S1);
    v[5]  = cmul(v[5],  W1);
    v[9]  = cmul(v[9],  W2);
    v[13] = cmul(v[13], W3);
    v[6]  = cmul(v[6],  W2);
    { float2 z = v[10]; v[10] = INV ? make_float2(-z.y, z.x) : make_float2(z.y, -z.x); }  // W4 = -/+ i
    v[14] = cmul(v[14], W6);
    v[7]  = cmul(v[7],  W3);
    v[11] = cmul(v[11], W6);
    v[15] = cmul(v[15], W9);
}

// input sample n at v[n]; output X_p at v[IDX16(p)]
template<bool INV>
__device__ __forceinline__ void dft16(float2* v) {
    #pragma unroll
    for (int n1 = 0; n1 < 4; ++n1) dft4<INV>(v, n1, 4);
    tw16<INV>(v);
    #pragma unroll
    for (int k2 = 0; k2 < 4; ++k2) dft4<INV>(v, 4 * k2, 1);
}

// input sample n at v[IDX16(n)]; output X_p at v[p]
template<bool INV>
__device__ __forceinline__ void dft16_perm(float2* v) {
    #pragma unroll
    for (int n1 = 0; n1 < 4; ++n1) dft4<INV>(v, 4 * n1, 1);
    tw16<INV>(v);
    #pragma unroll
    for (int k2 = 0; k2 < 4; ++k2) dft4<INV>(v, k2, 4);
}

// ---------------------------------------------------------------------------
// prep: full Hermitian spectrum H[0..N), twiddle table tw[0..N), and the
// TRANSPOSED stage-A twiddle table twA[p*256+t] = W_N^{t*p} (coalesced reads;
// measured win in round 3).
// ---------------------------------------------------------------------------
__global__ void prep_kernel(const float* __restrict__ wr, const float* __restrict__ wi,
                            float2* __restrict__ H, float2* __restrict__ tw) {
    int i = blockIdx.x * blockDim.x + threadIdx.x;
    if (i < N) {
        double ang = -2.0 * M_PI * (double)i / (double)N;
        tw[i] = make_float2((float)cos(ang), (float)sin(ang));
        float re, im;
        if (i <= N / 2) {
            re = wr[i];
            im = (i == N / 2) ? 0.0f : wi[i];
        } else {
            re = wr[N - i];
            im = -wi[N - i];
        }
        H[i] = make_float2(re, im);
    }
}

__global__ void prep_twA_kernel(float2* __restrict__ twA) {
    int i = blockIdx.x * blockDim.x + threadIdx.x;   // i in [0, 4096)
    int p = i >> 8, t = i & 255;
    double ang = -2.0 * M_PI * (double)(t * p) / (double)N;
    twA[i] = make_float2((float)cos(ang), (float)sin(ang));
}

// ---------------------------------------------------------------------------
// One block = 4 rows = TWO independent complex sequences (za = r0 + i*r1,
// zb = r2 + i*r3). Round-5 change vs the measured-good round-4 kernel
// (106 us): SAME buffers, access families, swizzle, tables, per-seq math,
// LDS op count -- only the SCHEDULE changes. Seq B runs one stage behind
// seq A, so every barrier interval is {read other-buf, full compute stage
// of one seq, write own-buf}: the barrier wait and the ds_read latency are
// covered by in-wave independent compute instead of being exposed (r4: all
// compute sat between the read and write bursts, leaving every post-write
// barrier empty-handed).
//   S1=fwdA  S2=fwdB  S3=fwdC+H+invA(fused)  S4=invB  S5=invC+store
//   S1(A),W(A) |s| R(A),S1(B),W(B) |s| R(B),S2(A),W(A) |s| R(A),S2(B),W(B)
//   |s| R(B),S3(A),W(A) |s| R(A),S3(B),W(B) |s| R(B),S4(A),W(A) |s|
//   R(A),S4(B),W(B) |s| R(B),S5(A)+store, S5(B)+store      (8 barriers)
// Hazards: each buffer's reads and next in-place writes are separated by
// one sync; each seq's regs are refilled by R exactly one interval after
// being consumed by W. Occupancy is LDS-bound (2 blocks/CU) so register
// creep above 128 is free; spill tripwire = WRITE_SIZE >> 131 MB.
// ---------------------------------------------------------------------------
__global__ __launch_bounds__(THREADS, 2) void fft_conv_kernel(
        const float* __restrict__ x, const float2* __restrict__ H,
        const float2* __restrict__ tw, const float2* __restrict__ twA,
        const float* __restrict__ bias, float* __restrict__ out) {
    __shared__ float2 lds[2 * N];   // 64 KB
    float2* __restrict__ ldsA = lds;
    float2* __restrict__ ldsB = lds + N;
    const int t = threadIdx.x;
    const int k = t & 15, j = t >> 4;
    const long base1 = (long)(4 * blockIdx.x) * N;  // row 4b
    const long base2 = base1 + N;                   // row 4b+1
    const long base3 = base1 + 2 * N;               // row 4b+2
    const long base4 = base1 + 3 * N;               // row 4b+3

    float2 va[16], vb[16];

    // ---- global loads for both sequences (pattern t+256r, coalesced) ----
    #pragma unroll
    for (int r = 0; r < 16; ++r) {
        va[r].x = x[base1 + t + 256 * r];
        va[r].y = x[base2 + t + 256 * r];
    }
    #pragma unroll
    for (int r = 0; r < 16; ++r) {
        vb[r].x = x[base3 + t + 256 * r];
        vb[r].y = x[base4 + t + 256 * r];
    }

    // ======== interval 0: S1(A) ========
    dft16<false>(va);
    #pragma unroll
    for (int p = 1; p < 16; ++p)
        va[IDX16(p)] = cmul(va[IDX16(p)], twA[p * 256 + t]);
    #pragma unroll
    for (int p = 0; p < 16; ++p) ldsA[SWZ(16 * t + p)] = va[IDX16(p)];
    __syncthreads();                                            // (1)

    // ======== interval 1: R(A), S1(B) ========
    #pragma unroll
    for (int r = 0; r < 16; ++r) va[r] = ldsA[SWZ(t + 256 * r)];
    dft16<false>(vb);
    #pragma unroll
    for (int p = 1; p < 16; ++p)
        vb[IDX16(p)] = cmul(vb[IDX16(p)], twA[p * 256 + t]);
    #pragma unroll
    for (int p = 0; p < 16; ++p) ldsB[SWZ(16 * t + p)] = vb[IDX16(p)];
    __syncthreads();                                            // (2)

    // ======== interval 2: R(B), S2(A) ========
    #pragma unroll
    for (int r = 0; r < 16; ++r) vb[r] = ldsB[SWZ(t + 256 * r)];
    dft16<false>(va);
    #pragma unroll
    for (int p = 1; p < 16; ++p)
        va[IDX16(p)] = cmul(va[IDX16(p)], tw[16 * j * p]);
    #pragma unroll
    for (int p = 0; p < 16; ++p) ldsA[SWZ(k + 256 * j + 16 * p)] = va[IDX16(p)];
    __syncthreads();                                            // (3)

    // ======== interval 3: R(A), S2(B) ========
    #pragma unroll
    for (int r = 0; r < 16; ++r) va[r] = ldsA[SWZ(t + 256 * r)];
    dft16<false>(vb);
    #pragma unroll
    for (int p = 1; p < 16; ++p)
        vb[IDX16(p)] = cmul(vb[IDX16(p)], tw[16 * j * p]);
    #pragma unroll
    for (int p = 0; p < 16; ++p) ldsB[SWZ(k + 256 * j + 16 * p)] = vb[IDX16(p)];
    __syncthreads();                                            // (4)

    // ======== interval 4: R(B), S3(A) = fwdC + H + invA ========
    #pragma unroll
    for (int r = 0; r < 16; ++r) vb[r] = ldsB[SWZ(t + 256 * r)];
    dft16<false>(va);
    #pragma unroll
    for (int q = 0; q < 16; ++q)
        va[q] = cmul(va[q], H[t + 256 * IDX16(q)]);
    dft16_perm<true>(va);                                       // X_p at slot p
    #pragma unroll
    for (int p = 1; p < 16; ++p) {
        float2 w = twA[p * 256 + t]; w.y = -w.y;
        va[p] = cmul(va[p], w);
    }
    #pragma unroll
    for (int p = 0; p < 16; ++p) ldsA[SWZ(16 * t + p)] = va[p];
    __syncthreads();                                            // (5)

    // ======== interval 5: R(A), S3(B) ========
    #pragma unroll
    for (int r = 0; r < 16; ++r) va[r] = ldsA[SWZ(t + 256 * r)];
    dft16<false>(vb);
    #pragma unroll
    for (int q = 0; q < 16; ++q)
        vb[q] = cmul(vb[q], H[t + 256 * IDX16(q)]);
    dft16_perm<true>(vb);
    #pragma unroll
    for (int p = 1; p < 16; ++p) {
        float2 w = twA[p * 256 + t]; w.y = -w.y;
        vb[p] = cmul(vb[p], w);
    }
    #pragma unroll
    for (int p = 0; p < 16; ++p) ldsB[SWZ(16 * t + p)] = vb[p];
    __syncthreads();                                            // (6)

    // ======== interval 6: R(B), S4(A) = invB ========
    #pragma unroll
    for (int r = 0; r < 16; ++r) vb[r] = ldsB[SWZ(t + 256 * r)];
    dft16<true>(va);
    #pragma unroll
    for (int p = 1; p < 16; ++p) {
        float2 w = tw[16 * j * p]; w.y = -w.y;
        va[IDX16(p)] = cmul(va[IDX16(p)], w);
    }
    #pragma unroll
    for (int p = 0; p < 16; ++p) ldsA[SWZ(k + 256 * j + 16 * p)] = va[IDX16(p)];
    __syncthreads();                                            // (7)

    // ======== interval 7: R(A), S4(B) ========
    #pragma unroll
    for (int r = 0; r < 16; ++r) va[r] = ldsA[SWZ(t + 256 * r)];
    dft16<true>(vb);
    #pragma unroll
    for (int p = 1; p < 16; ++p) {
        float2 w = tw[16 * j * p]; w.y = -w.y;
        vb[IDX16(p)] = cmul(vb[IDX16(p)], w);
    }
    #pragma unroll
    for (int p = 0; p < 16; ++p) ldsB[SWZ(k + 256 * j + 16 * p)] = vb[IDX16(p)];
    __syncthreads();                                            // (8)

    // ======== interval 8: R(B), S5(A) = invC + store ========
    #pragma unroll
    for (int r = 0; r < 16; ++r) vb[r] = ldsB[SWZ(t + 256 * r)];
    dft16<true>(va);
    const float inv = 1.0f / (float)N;
    #pragma unroll
    for (int p = 0; p < 16; ++p) {
        float2 a = va[IDX16(p)];
        float bb = bias[t + 256 * p];
        out[base1 + t + 256 * p] = fmaf(a.x, inv, bb);
        out[base2 + t + 256 * p] = fmaf(a.y, inv, bb);
    }

    // ======== interval 9: S5(B) ========
    dft16<true>(vb);
    #pragma unroll
    for (int p = 0; p < 16; ++p) {
        float2 b = vb[IDX16(p)];
        float bb = bias[t + 256 * p];
        out[base3 + t + 256 * p] = fmaf(b.x, inv, bb);
        out[base4 + t + 256 * p] = fmaf(b.y, inv, bb);
    }
}

// ---------------------------------------------------------------------------
extern "C" void kernel_launch(void* const* d_in, const int* in_sizes, int n_in,
                              void* d_out, int out_size, void* d_ws, size_t ws_size,
                              hipStream_t stream) {
    const float* x  = (const float*)d_in[0];   // (8192, 4096)
    const float* wr = (const float*)d_in[1];   // (2049,)
    const float* wi = (const float*)d_in[2];   // (2049,)
    const float* bs = (const float*)d_in[3];   // (4096,)
    float* out = (float*)d_out;                // (8192, 4096)

    float2* H   = (float2*)d_ws;                                           // 32 KB
    float2* tw  = (float2*)((char*)d_ws + (size_t)N * sizeof(float2));     // 32 KB
    float2* twA = (float2*)((char*)d_ws + (size_t)2 * N * sizeof(float2)); // 32 KB

    prep_kernel<<<dim3(N / THREADS), dim3(THREADS), 0, stream>>>(wr, wi, H, tw);
    prep_twA_kernel<<<dim3(N / THREADS), dim3(THREADS), 0, stream>>>(twA);
    fft_conv_kernel<<<dim3(BATCH / 4), dim3(THREADS), 0, stream>>>(x, H, tw, twA, bs, out);
}